// Round 4
// baseline (387.137 us; speedup 1.0000x reference)
//
#include <hip/hip_runtime.h>
#include <hip/hip_bf16.h>

// out[tgt[i], :] += x[src[i], :] * e[i]   (fp32, D=32)
// Two-level radix partition by target bucket, then LDS-accumulated apply.
// No fp32 global atomics; all record writes are block-sequential.

#define D_FEAT   32
#define SHIFT    7            // 128 nodes per bucket
#define BNODES   128
#define CHUNK    8192         // edges per partition block
#define MAXNB    1024

// ---------------- fallback path (round-2, verified) ----------------
__global__ void zero_out_kernel(float* __restrict__ out, int n) {
    int i = blockIdx.x * blockDim.x + threadIdx.x;
    if (i < n) out[i] = 0.0f;
}

__global__ void scatter_add_kernel(const float* __restrict__ x,
                                   const int* __restrict__ src,
                                   const int* __restrict__ tgt,
                                   const float* __restrict__ e,
                                   float* __restrict__ out,
                                   int n_edges) {
    long long gid   = (long long)blockIdx.x * blockDim.x + threadIdx.x;
    long long total = (long long)n_edges * D_FEAT;
    if (gid >= total) return;
    int edge = (int)(gid >> 5);
    int f    = (int)(gid & 31);
    float m = x[(long long)src[edge] * D_FEAT + f] * e[edge];
    atomicAdd(&out[(long long)tgt[edge] * D_FEAT + f], m);
}

// ---------------- radix path ----------------

// per-chunk histogram of target buckets -> Hg[bucket*nchunks + chunk]
__global__ void p1_hist_kernel(const int* __restrict__ tgt, int* __restrict__ Hg,
                               int n_edges, int NB, int nchunks) {
    __shared__ int cnt[MAXNB];
    for (int i = threadIdx.x; i < NB; i += 256) cnt[i] = 0;
    __syncthreads();
    int base = blockIdx.x * CHUNK;
    int lim  = min(base + CHUNK, n_edges);
    for (int i = base + threadIdx.x; i < lim; i += 256)
        atomicAdd(&cnt[tgt[i] >> SHIFT], 1);
    __syncthreads();
    for (int i = threadIdx.x; i < NB; i += 256)
        Hg[i * nchunks + blockIdx.x] = cnt[i];
}

// in-place per-256-chunk exclusive scan; chunk totals to bsum
__global__ void scan_block_kernel(int* __restrict__ data, int* __restrict__ bsum,
                                  int n) {
    __shared__ int s[256];
    int i = blockIdx.x * 256 + threadIdx.x;
    int v = (i < n) ? data[i] : 0;
    s[threadIdx.x] = v;
    __syncthreads();
    #pragma unroll
    for (int d = 1; d < 256; d <<= 1) {
        int t = (threadIdx.x >= d) ? s[threadIdx.x - d] : 0;
        __syncthreads();
        s[threadIdx.x] += t;
        __syncthreads();
    }
    if (i < n) data[i] = s[threadIdx.x] - v;           // exclusive within chunk
    if (threadIdx.x == 255) bsum[blockIdx.x] = s[255]; // chunk total
}

__global__ void scan_bsum_kernel(int* __restrict__ bsum, int nblk) {
    __shared__ int s[1024];
    int tid = threadIdx.x;
    int v = (tid < nblk) ? bsum[tid] : 0;
    s[tid] = v;
    __syncthreads();
    for (int d = 1; d < 1024; d <<= 1) {
        int t = (tid >= d) ? s[tid - d] : 0;
        __syncthreads();
        s[tid] += t;
        __syncthreads();
    }
    if (tid < nblk) bsum[tid] = s[tid] - v;            // exclusive
}

__global__ void add_base_kernel(int* __restrict__ data, const int* __restrict__ bsum,
                                int n) {
    int i = blockIdx.x * 256 + threadIdx.x;
    if (i < n) data[i] += bsum[blockIdx.x];
}

// scatter records into (chunk,bucket)-exclusive regions via LDS cursors.
// rec = { src | (local_tgt << 17) , bits(e) }  (src < 2^17, local_tgt < 128)
__global__ void p1_scatter_kernel(const int* __restrict__ src,
                                  const int* __restrict__ tgt,
                                  const float* __restrict__ e,
                                  const int* __restrict__ Hg,
                                  int2* __restrict__ rec,
                                  int n_edges, int NB, int nchunks) {
    __shared__ int cur[MAXNB];
    for (int i = threadIdx.x; i < NB; i += 256)
        cur[i] = Hg[i * nchunks + blockIdx.x];
    __syncthreads();
    int base = blockIdx.x * CHUNK;
    int lim  = min(base + CHUNK, n_edges);
    for (int i = base + threadIdx.x; i < lim; i += 256) {
        int t = tgt[i];
        int b = t >> SHIFT;
        int pos = atomicAdd(&cur[b], 1);
        rec[pos] = make_int2(src[i] | ((t & (BNODES - 1)) << 17),
                             __float_as_int(e[i]));
    }
}

// one block per bucket: accumulate into LDS slice, write coalesced.
__global__ __launch_bounds__(256) void p2_apply_kernel(
        const float* __restrict__ x, const int2* __restrict__ rec,
        const int* __restrict__ Hg, float* __restrict__ out,
        int n_edges, int n_nodes, int NB, int nchunks) {
    __shared__ float acc[BNODES * D_FEAT];   // 16 KB
    for (int i = threadIdx.x; i < BNODES * D_FEAT; i += 256) acc[i] = 0.0f;
    int b    = blockIdx.x;
    int base = Hg[b * nchunks];
    int end  = (b + 1 < NB) ? Hg[(b + 1) * nchunks] : n_edges;
    __syncthreads();

    int f = threadIdx.x & 31;
    int r = base + (threadIdx.x >> 5);       // 8 records per block-step

    for (; r + 24 < end; r += 32) {          // unroll x4 for memory-level parallelism
        int2 a0 = rec[r];
        int2 a1 = rec[r + 8];
        int2 a2 = rec[r + 16];
        int2 a3 = rec[r + 24];
        float v0 = x[(a0.x & 0x1FFFF) * D_FEAT + f] * __int_as_float(a0.y);
        float v1 = x[(a1.x & 0x1FFFF) * D_FEAT + f] * __int_as_float(a1.y);
        float v2 = x[(a2.x & 0x1FFFF) * D_FEAT + f] * __int_as_float(a2.y);
        float v3 = x[(a3.x & 0x1FFFF) * D_FEAT + f] * __int_as_float(a3.y);
        atomicAdd(&acc[((a0.x >> 17) & (BNODES - 1)) * D_FEAT + f], v0);
        atomicAdd(&acc[((a1.x >> 17) & (BNODES - 1)) * D_FEAT + f], v1);
        atomicAdd(&acc[((a2.x >> 17) & (BNODES - 1)) * D_FEAT + f], v2);
        atomicAdd(&acc[((a3.x >> 17) & (BNODES - 1)) * D_FEAT + f], v3);
    }
    for (; r < end; r += 8) {
        int2 a = rec[r];
        float v = x[(a.x & 0x1FFFF) * D_FEAT + f] * __int_as_float(a.y);
        atomicAdd(&acc[((a.x >> 17) & (BNODES - 1)) * D_FEAT + f], v);
    }
    __syncthreads();

    int out0 = b << SHIFT;                   // first node of bucket
    for (int i = threadIdx.x; i < BNODES * D_FEAT; i += 256) {
        int node = out0 + (i >> 5);
        if (node < n_nodes) out[(long long)out0 * D_FEAT + i] = acc[i];
    }
}

extern "C" void kernel_launch(void* const* d_in, const int* in_sizes, int n_in,
                              void* d_out, int out_size, void* d_ws, size_t ws_size,
                              hipStream_t stream) {
    const float* x = (const float*)d_in[0];
    const int*   a = (const int*)d_in[1];     // [2, n_edges] delivered as int32
    const float* e = (const float*)d_in[2];

    int n_edges = in_sizes[2];
    int n_nodes = out_size / D_FEAT;
    const int* src = a;
    const int* tgt = a + n_edges;
    float* out = (float*)d_out;

    int NB        = (n_nodes + BNODES - 1) >> SHIFT;
    int nchunks   = (n_edges + CHUNK - 1) / CHUNK;
    int scan_n    = NB * nchunks;
    int nblk_scan = (scan_n + 255) / 256;

    size_t rec_bytes  = (size_t)n_edges * sizeof(int2);
    size_t hg_bytes   = (size_t)scan_n * sizeof(int);
    size_t bsum_bytes = (size_t)nblk_scan * sizeof(int);
    size_t need = rec_bytes + hg_bytes + bsum_bytes;

    bool ok = (ws_size >= need) && (NB <= MAXNB) && (nblk_scan <= 1024) &&
              (n_nodes <= (1 << 17));
    if (!ok) {
        // fallback: direct atomics (verified round 2, 171 us)
        int threads = 256;
        zero_out_kernel<<<(out_size + threads - 1) / threads, threads, 0, stream>>>(out, out_size);
        long long total = (long long)n_edges * D_FEAT;
        int blocks = (int)((total + threads - 1) / threads);
        scatter_add_kernel<<<blocks, threads, 0, stream>>>(x, src, tgt, e, out, n_edges);
        return;
    }

    char* p = (char*)d_ws;
    int2* rec  = (int2*)p; p += rec_bytes;   // 8B-aligned first
    int*  Hg   = (int*)p;  p += hg_bytes;
    int*  bsum = (int*)p;

    p1_hist_kernel<<<nchunks, 256, 0, stream>>>(tgt, Hg, n_edges, NB, nchunks);
    scan_block_kernel<<<nblk_scan, 256, 0, stream>>>(Hg, bsum, scan_n);
    scan_bsum_kernel<<<1, 1024, 0, stream>>>(bsum, nblk_scan);
    add_base_kernel<<<nblk_scan, 256, 0, stream>>>(Hg, bsum, scan_n);
    p1_scatter_kernel<<<nchunks, 256, 0, stream>>>(src, tgt, e, Hg, rec, n_edges, NB, nchunks);
    p2_apply_kernel<<<NB, 256, 0, stream>>>(x, rec, Hg, out, n_edges, n_nodes, NB, nchunks);
}

// Round 5
// 381.467 us; speedup vs baseline: 1.0149x; 1.0149x over previous
//
#include <hip/hip_runtime.h>
#include <hip/hip_bf16.h>

// out[tgt[i], :] += x[src[i], :] * e[i]   (fp32, D=32)
// Two-level radix partition by target bucket, then LDS-accumulated apply.
// No fp32 global atomics; all record writes are block-sequential.
// Round 5: apply kernel widened to 1024 threads (32 record streams x4 unroll)
// to fix latency starvation (was 21% occupancy, 343 us).

#define D_FEAT   32
#define SHIFT    7            // 128 nodes per bucket
#define BNODES   128
#define CHUNK    8192         // edges per partition block
#define MAXNB    1024

// ---------------- fallback path (round-2, verified) ----------------
__global__ void zero_out_kernel(float* __restrict__ out, int n) {
    int i = blockIdx.x * blockDim.x + threadIdx.x;
    if (i < n) out[i] = 0.0f;
}

__global__ void scatter_add_kernel(const float* __restrict__ x,
                                   const int* __restrict__ src,
                                   const int* __restrict__ tgt,
                                   const float* __restrict__ e,
                                   float* __restrict__ out,
                                   int n_edges) {
    long long gid   = (long long)blockIdx.x * blockDim.x + threadIdx.x;
    long long total = (long long)n_edges * D_FEAT;
    if (gid >= total) return;
    int edge = (int)(gid >> 5);
    int f    = (int)(gid & 31);
    float m = x[(long long)src[edge] * D_FEAT + f] * e[edge];
    atomicAdd(&out[(long long)tgt[edge] * D_FEAT + f], m);
}

// ---------------- radix path ----------------

// per-chunk histogram of target buckets -> Hg[bucket*nchunks + chunk]
__global__ void p1_hist_kernel(const int* __restrict__ tgt, int* __restrict__ Hg,
                               int n_edges, int NB, int nchunks) {
    __shared__ int cnt[MAXNB];
    for (int i = threadIdx.x; i < NB; i += 256) cnt[i] = 0;
    __syncthreads();
    int base = blockIdx.x * CHUNK;
    int lim  = min(base + CHUNK, n_edges);
    for (int i = base + threadIdx.x; i < lim; i += 256)
        atomicAdd(&cnt[tgt[i] >> SHIFT], 1);
    __syncthreads();
    for (int i = threadIdx.x; i < NB; i += 256)
        Hg[i * nchunks + blockIdx.x] = cnt[i];
}

// in-place per-256-chunk exclusive scan; chunk totals to bsum
__global__ void scan_block_kernel(int* __restrict__ data, int* __restrict__ bsum,
                                  int n) {
    __shared__ int s[256];
    int i = blockIdx.x * 256 + threadIdx.x;
    int v = (i < n) ? data[i] : 0;
    s[threadIdx.x] = v;
    __syncthreads();
    #pragma unroll
    for (int d = 1; d < 256; d <<= 1) {
        int t = (threadIdx.x >= d) ? s[threadIdx.x - d] : 0;
        __syncthreads();
        s[threadIdx.x] += t;
        __syncthreads();
    }
    if (i < n) data[i] = s[threadIdx.x] - v;           // exclusive within chunk
    if (threadIdx.x == 255) bsum[blockIdx.x] = s[255]; // chunk total
}

__global__ void scan_bsum_kernel(int* __restrict__ bsum, int nblk) {
    __shared__ int s[1024];
    int tid = threadIdx.x;
    int v = (tid < nblk) ? bsum[tid] : 0;
    s[tid] = v;
    __syncthreads();
    for (int d = 1; d < 1024; d <<= 1) {
        int t = (tid >= d) ? s[tid - d] : 0;
        __syncthreads();
        s[tid] += t;
        __syncthreads();
    }
    if (tid < nblk) bsum[tid] = s[tid] - v;            // exclusive
}

__global__ void add_base_kernel(int* __restrict__ data, const int* __restrict__ bsum,
                                int n) {
    int i = blockIdx.x * 256 + threadIdx.x;
    if (i < n) data[i] += bsum[blockIdx.x];
}

// scatter records into (chunk,bucket)-exclusive regions via LDS cursors.
// rec = { src | (local_tgt << 17) , bits(e) }  (src < 2^17, local_tgt < 128)
__global__ void p1_scatter_kernel(const int* __restrict__ src,
                                  const int* __restrict__ tgt,
                                  const float* __restrict__ e,
                                  const int* __restrict__ Hg,
                                  int2* __restrict__ rec,
                                  int n_edges, int NB, int nchunks) {
    __shared__ int cur[MAXNB];
    for (int i = threadIdx.x; i < NB; i += 256)
        cur[i] = Hg[i * nchunks + blockIdx.x];
    __syncthreads();
    int base = blockIdx.x * CHUNK;
    int lim  = min(base + CHUNK, n_edges);
    for (int i = base + threadIdx.x; i < lim; i += 256) {
        int t = tgt[i];
        int b = t >> SHIFT;
        int pos = atomicAdd(&cur[b], 1);
        rec[pos] = make_int2(src[i] | ((t & (BNODES - 1)) << 17),
                             __float_as_int(e[i]));
    }
}

// one 1024-thread block per bucket: 32 record streams, accumulate into LDS,
// write coalesced. Writes every node -> no pre-zero needed.
__global__ __launch_bounds__(1024) void p2_apply_kernel(
        const float* __restrict__ x, const int2* __restrict__ rec,
        const int* __restrict__ Hg, float* __restrict__ out,
        int n_edges, int n_nodes, int NB, int nchunks) {
    __shared__ float acc[BNODES * D_FEAT];   // 16 KB
    for (int i = threadIdx.x; i < BNODES * D_FEAT; i += 1024) acc[i] = 0.0f;
    int b    = blockIdx.x;
    int base = Hg[b * nchunks];
    int end  = (b + 1 < NB) ? Hg[(b + 1) * nchunks] : n_edges;
    __syncthreads();

    int f = threadIdx.x & 31;
    int r = base + (threadIdx.x >> 5);       // 32 record streams per block

    for (; r + 96 < end; r += 128) {         // x4 unroll: 128 gathers in flight
        int2 a0 = rec[r];
        int2 a1 = rec[r + 32];
        int2 a2 = rec[r + 64];
        int2 a3 = rec[r + 96];
        float v0 = x[(a0.x & 0x1FFFF) * D_FEAT + f] * __int_as_float(a0.y);
        float v1 = x[(a1.x & 0x1FFFF) * D_FEAT + f] * __int_as_float(a1.y);
        float v2 = x[(a2.x & 0x1FFFF) * D_FEAT + f] * __int_as_float(a2.y);
        float v3 = x[(a3.x & 0x1FFFF) * D_FEAT + f] * __int_as_float(a3.y);
        atomicAdd(&acc[((a0.x >> 17) & (BNODES - 1)) * D_FEAT + f], v0);
        atomicAdd(&acc[((a1.x >> 17) & (BNODES - 1)) * D_FEAT + f], v1);
        atomicAdd(&acc[((a2.x >> 17) & (BNODES - 1)) * D_FEAT + f], v2);
        atomicAdd(&acc[((a3.x >> 17) & (BNODES - 1)) * D_FEAT + f], v3);
    }
    for (; r < end; r += 32) {
        int2 a = rec[r];
        float v = x[(a.x & 0x1FFFF) * D_FEAT + f] * __int_as_float(a.y);
        atomicAdd(&acc[((a.x >> 17) & (BNODES - 1)) * D_FEAT + f], v);
    }
    __syncthreads();

    int out0 = b << SHIFT;                   // first node of bucket
    for (int i = threadIdx.x; i < BNODES * D_FEAT; i += 1024) {
        int node = out0 + (i >> 5);
        if (node < n_nodes) out[(long long)out0 * D_FEAT + i] = acc[i];
    }
}

extern "C" void kernel_launch(void* const* d_in, const int* in_sizes, int n_in,
                              void* d_out, int out_size, void* d_ws, size_t ws_size,
                              hipStream_t stream) {
    const float* x = (const float*)d_in[0];
    const int*   a = (const int*)d_in[1];     // [2, n_edges] delivered as int32
    const float* e = (const float*)d_in[2];

    int n_edges = in_sizes[2];
    int n_nodes = out_size / D_FEAT;
    const int* src = a;
    const int* tgt = a + n_edges;
    float* out = (float*)d_out;

    int NB        = (n_nodes + BNODES - 1) >> SHIFT;
    int nchunks   = (n_edges + CHUNK - 1) / CHUNK;
    int scan_n    = NB * nchunks;
    int nblk_scan = (scan_n + 255) / 256;

    size_t rec_bytes  = (size_t)n_edges * sizeof(int2);
    size_t hg_bytes   = (size_t)scan_n * sizeof(int);
    size_t bsum_bytes = (size_t)nblk_scan * sizeof(int);
    size_t need = rec_bytes + hg_bytes + bsum_bytes;

    bool ok = (ws_size >= need) && (NB <= MAXNB) && (nblk_scan <= 1024) &&
              (n_nodes <= (1 << 17));
    if (!ok) {
        // fallback: direct atomics (verified round 2, 171 us)
        int threads = 256;
        zero_out_kernel<<<(out_size + threads - 1) / threads, threads, 0, stream>>>(out, out_size);
        long long total = (long long)n_edges * D_FEAT;
        int blocks = (int)((total + threads - 1) / threads);
        scatter_add_kernel<<<blocks, threads, 0, stream>>>(x, src, tgt, e, out, n_edges);
        return;
    }

    char* p = (char*)d_ws;
    int2* rec  = (int2*)p; p += rec_bytes;   // 8B-aligned first
    int*  Hg   = (int*)p;  p += hg_bytes;
    int*  bsum = (int*)p;

    p1_hist_kernel<<<nchunks, 256, 0, stream>>>(tgt, Hg, n_edges, NB, nchunks);
    scan_block_kernel<<<nblk_scan, 256, 0, stream>>>(Hg, bsum, scan_n);
    scan_bsum_kernel<<<1, 1024, 0, stream>>>(bsum, nblk_scan);
    add_base_kernel<<<nblk_scan, 256, 0, stream>>>(Hg, bsum, scan_n);
    p1_scatter_kernel<<<nchunks, 256, 0, stream>>>(src, tgt, e, Hg, rec, n_edges, NB, nchunks);
    p2_apply_kernel<<<NB, 1024, 0, stream>>>(x, rec, Hg, out, n_edges, n_nodes, NB, nchunks);
}

// Round 6
// 81.986 us; speedup vs baseline: 4.7220x; 4.6529x over previous
//
#include <hip/hip_runtime.h>
#include <hip/hip_bf16.h>

// out[tgt[i], :] += x[src[i], :] * e[i]   (fp32, D=32)
// Radix partition by 128-node target bucket, then per-bucket apply that
// sorts records by local node in LDS and accumulates in REGISTERS
// (round 5's per-feature ds_add_f32 was the fixed-rate serializer: 339us
// invariant to occupancy 21%->62%).

#define D_FEAT   32
#define SHIFT    7            // 128 nodes per bucket
#define BNODES   128
#define CHUNK    8192         // edges per partition block
#define MAXNB    1024
#define CAP      4096         // max records sortable in LDS per bucket

// ---------------- fallback path (round-2, verified) ----------------
__global__ void zero_out_kernel(float* __restrict__ out, int n) {
    int i = blockIdx.x * blockDim.x + threadIdx.x;
    if (i < n) out[i] = 0.0f;
}

__global__ void scatter_add_kernel(const float* __restrict__ x,
                                   const int* __restrict__ src,
                                   const int* __restrict__ tgt,
                                   const float* __restrict__ e,
                                   float* __restrict__ out,
                                   int n_edges) {
    long long gid   = (long long)blockIdx.x * blockDim.x + threadIdx.x;
    long long total = (long long)n_edges * D_FEAT;
    if (gid >= total) return;
    int edge = (int)(gid >> 5);
    int f    = (int)(gid & 31);
    float m = x[(long long)src[edge] * D_FEAT + f] * e[edge];
    atomicAdd(&out[(long long)tgt[edge] * D_FEAT + f], m);
}

// ---------------- radix path ----------------

// per-chunk histogram of target buckets -> Hg[bucket*nchunks + chunk]
__global__ void p1_hist_kernel(const int* __restrict__ tgt, int* __restrict__ Hg,
                               int n_edges, int NB, int nchunks) {
    __shared__ int cnt[MAXNB];
    for (int i = threadIdx.x; i < NB; i += 256) cnt[i] = 0;
    __syncthreads();
    int base = blockIdx.x * CHUNK;
    int lim  = min(base + CHUNK, n_edges);
    for (int i = base + threadIdx.x; i < lim; i += 256)
        atomicAdd(&cnt[tgt[i] >> SHIFT], 1);
    __syncthreads();
    for (int i = threadIdx.x; i < NB; i += 256)
        Hg[i * nchunks + blockIdx.x] = cnt[i];
}

// in-place per-256-chunk exclusive scan; chunk totals to bsum
__global__ void scan_block_kernel(int* __restrict__ data, int* __restrict__ bsum,
                                  int n) {
    __shared__ int s[256];
    int i = blockIdx.x * 256 + threadIdx.x;
    int v = (i < n) ? data[i] : 0;
    s[threadIdx.x] = v;
    __syncthreads();
    #pragma unroll
    for (int d = 1; d < 256; d <<= 1) {
        int t = (threadIdx.x >= d) ? s[threadIdx.x - d] : 0;
        __syncthreads();
        s[threadIdx.x] += t;
        __syncthreads();
    }
    if (i < n) data[i] = s[threadIdx.x] - v;           // exclusive within chunk
    if (threadIdx.x == 255) bsum[blockIdx.x] = s[255]; // chunk total
}

__global__ void scan_bsum_kernel(int* __restrict__ bsum, int nblk) {
    __shared__ int s[1024];
    int tid = threadIdx.x;
    int v = (tid < nblk) ? bsum[tid] : 0;
    s[tid] = v;
    __syncthreads();
    for (int d = 1; d < 1024; d <<= 1) {
        int t = (tid >= d) ? s[tid - d] : 0;
        __syncthreads();
        s[tid] += t;
        __syncthreads();
    }
    if (tid < nblk) bsum[tid] = s[tid] - v;            // exclusive
}

__global__ void add_base_kernel(int* __restrict__ data, const int* __restrict__ bsum,
                                int n) {
    int i = blockIdx.x * 256 + threadIdx.x;
    if (i < n) data[i] += bsum[blockIdx.x];
}

// scatter records into (chunk,bucket)-exclusive regions via LDS cursors.
// rec = { src | (local_tgt << 17) , bits(e) }  (src < 2^17, local_tgt < 128)
__global__ void p1_scatter_kernel(const int* __restrict__ src,
                                  const int* __restrict__ tgt,
                                  const float* __restrict__ e,
                                  const int* __restrict__ Hg,
                                  int2* __restrict__ rec,
                                  int n_edges, int NB, int nchunks) {
    __shared__ int cur[MAXNB];
    for (int i = threadIdx.x; i < NB; i += 256)
        cur[i] = Hg[i * nchunks + blockIdx.x];
    __syncthreads();
    int base = blockIdx.x * CHUNK;
    int lim  = min(base + CHUNK, n_edges);
    for (int i = base + threadIdx.x; i < lim; i += 256) {
        int t = tgt[i];
        int b = t >> SHIFT;
        int pos = atomicAdd(&cur[b], 1);
        rec[pos] = make_int2(src[i] | ((t & (BNODES - 1)) << 17),
                             __float_as_int(e[i]));
    }
}

// one 1024-thread block per bucket:
//  fast path: node-sort records into LDS, then register-accumulated gather
//  slow path (bucket > CAP records; unreachable for this input): ds_add acc
__global__ __launch_bounds__(1024) void p2_apply_kernel(
        const float* __restrict__ x, const int2* __restrict__ rec,
        const int* __restrict__ Hg, float* __restrict__ out,
        int n_edges, int n_nodes, int NB, int nchunks) {
    __shared__ int2 srt[CAP];          // 32 KB; aliased as fp32 acc in slow path
    __shared__ int  cnt[BNODES];
    __shared__ int  off[BNODES + 1];
    __shared__ int  cur[BNODES];
    __shared__ int  stmp[BNODES];

    int tid  = threadIdx.x;
    int b    = blockIdx.x;
    int base = Hg[b * nchunks];
    int end  = (b + 1 < NB) ? Hg[(b + 1) * nchunks] : n_edges;
    int nrec = end - base;

    if (nrec <= CAP) {
        // ---- pass 1: per-node counts (small LDS histogram) ----
        if (tid < BNODES) cnt[tid] = 0;
        __syncthreads();
        for (int r = base + tid; r < end; r += 1024) {
            int2 a = rec[r];
            atomicAdd(&cnt[(a.x >> 17) & (BNODES - 1)], 1);
        }
        __syncthreads();
        // ---- 128-entry exclusive scan ----
        int v = (tid < BNODES) ? cnt[tid] : 0;
        if (tid < BNODES) stmp[tid] = v;
        __syncthreads();
        #pragma unroll
        for (int d = 1; d < BNODES; d <<= 1) {
            int t = (tid < BNODES && tid >= d) ? stmp[tid - d] : 0;
            __syncthreads();
            if (tid < BNODES) stmp[tid] += t;
            __syncthreads();
        }
        if (tid < BNODES) { off[tid] = stmp[tid] - v; cur[tid] = stmp[tid] - v; }
        if (tid == 0) off[BNODES] = nrec;
        __syncthreads();
        // ---- pass 2: scatter records node-sorted into LDS ----
        for (int r = base + tid; r < end; r += 1024) {
            int2 a = rec[r];
            int pos = atomicAdd(&cur[(a.x >> 17) & (BNODES - 1)], 1);
            srt[pos] = a;
        }
        __syncthreads();
        // ---- gather: 32 groups x 4 nodes, register accumulate ----
        int f = tid & 31;
        int g = tid >> 5;
        for (int ln = g; ln < BNODES; ln += 32) {
            int p  = off[ln];
            int pe = off[ln + 1];
            float acc = 0.0f;
            for (; p + 3 < pe; p += 4) {      // 4 independent gathers in flight
                int2 r0 = srt[p];
                int2 r1 = srt[p + 1];
                int2 r2 = srt[p + 2];
                int2 r3 = srt[p + 3];
                float v0 = x[(r0.x & 0x1FFFF) * D_FEAT + f] * __int_as_float(r0.y);
                float v1 = x[(r1.x & 0x1FFFF) * D_FEAT + f] * __int_as_float(r1.y);
                float v2 = x[(r2.x & 0x1FFFF) * D_FEAT + f] * __int_as_float(r2.y);
                float v3 = x[(r3.x & 0x1FFFF) * D_FEAT + f] * __int_as_float(r3.y);
                acc += (v0 + v1) + (v2 + v3);
            }
            for (; p < pe; ++p) {
                int2 r0 = srt[p];
                acc += x[(r0.x & 0x1FFFF) * D_FEAT + f] * __int_as_float(r0.y);
            }
            int node = (b << SHIFT) + ln;
            if (node < n_nodes)
                out[(long long)node * D_FEAT + f] = acc;   // zero for isolated nodes
        }
    } else {
        // ---- slow path: LDS fp32 accumulate (correctness only) ----
        float* accS = (float*)srt;     // 16 KB of the 32 KB buffer
        for (int i = tid; i < BNODES * D_FEAT; i += 1024) accS[i] = 0.0f;
        __syncthreads();
        int f = tid & 31;
        for (int r = base + (tid >> 5); r < end; r += 32) {
            int2 a = rec[r];
            float v = x[(a.x & 0x1FFFF) * D_FEAT + f] * __int_as_float(a.y);
            atomicAdd(&accS[((a.x >> 17) & (BNODES - 1)) * D_FEAT + f], v);
        }
        __syncthreads();
        int out0 = b << SHIFT;
        for (int i = tid; i < BNODES * D_FEAT; i += 1024) {
            int node = out0 + (i >> 5);
            if (node < n_nodes) out[(long long)out0 * D_FEAT + i] = accS[i];
        }
    }
}

extern "C" void kernel_launch(void* const* d_in, const int* in_sizes, int n_in,
                              void* d_out, int out_size, void* d_ws, size_t ws_size,
                              hipStream_t stream) {
    const float* x = (const float*)d_in[0];
    const int*   a = (const int*)d_in[1];     // [2, n_edges] delivered as int32
    const float* e = (const float*)d_in[2];

    int n_edges = in_sizes[2];
    int n_nodes = out_size / D_FEAT;
    const int* src = a;
    const int* tgt = a + n_edges;
    float* out = (float*)d_out;

    int NB        = (n_nodes + BNODES - 1) >> SHIFT;
    int nchunks   = (n_edges + CHUNK - 1) / CHUNK;
    int scan_n    = NB * nchunks;
    int nblk_scan = (scan_n + 255) / 256;

    size_t rec_bytes  = (size_t)n_edges * sizeof(int2);
    size_t hg_bytes   = (size_t)scan_n * sizeof(int);
    size_t bsum_bytes = (size_t)nblk_scan * sizeof(int);
    size_t need = rec_bytes + hg_bytes + bsum_bytes;

    bool ok = (ws_size >= need) && (NB <= MAXNB) && (nblk_scan <= 1024) &&
              (n_nodes <= (1 << 17));
    if (!ok) {
        // fallback: direct atomics (verified round 2, 171 us)
        int threads = 256;
        zero_out_kernel<<<(out_size + threads - 1) / threads, threads, 0, stream>>>(out, out_size);
        long long total = (long long)n_edges * D_FEAT;
        int blocks = (int)((total + threads - 1) / threads);
        scatter_add_kernel<<<blocks, threads, 0, stream>>>(x, src, tgt, e, out, n_edges);
        return;
    }

    char* p = (char*)d_ws;
    int2* rec  = (int2*)p; p += rec_bytes;   // 8B-aligned first
    int*  Hg   = (int*)p;  p += hg_bytes;
    int*  bsum = (int*)p;

    p1_hist_kernel<<<nchunks, 256, 0, stream>>>(tgt, Hg, n_edges, NB, nchunks);
    scan_block_kernel<<<nblk_scan, 256, 0, stream>>>(Hg, bsum, scan_n);
    scan_bsum_kernel<<<1, 1024, 0, stream>>>(bsum, nblk_scan);
    add_base_kernel<<<nblk_scan, 256, 0, stream>>>(Hg, bsum, scan_n);
    p1_scatter_kernel<<<nchunks, 256, 0, stream>>>(src, tgt, e, Hg, rec, n_edges, NB, nchunks);
    p2_apply_kernel<<<NB, 1024, 0, stream>>>(x, rec, Hg, out, n_edges, n_nodes, NB, nchunks);
}

// Round 7
// 68.906 us; speedup vs baseline: 5.6183x; 1.1898x over previous
//
#include <hip/hip_runtime.h>
#include <hip/hip_bf16.h>

// out[tgt[i], :] += x[src[i], :] * e[i]   (fp32, D=32)
// Radix partition by 128-node target bucket, then per-bucket apply that
// sorts records by local node in LDS and accumulates in REGISTERS.
// Round 7: hist/scatter widened to 1024 threads (scatter was wave-starved:
// 6.5% occupancy, 46us, VALUBusy 0.9%).

#define D_FEAT   32
#define SHIFT    7            // 128 nodes per bucket
#define BNODES   128
#define CHUNK    8192         // edges per partition block
#define MAXNB    1024
#define CAP      4096         // max records sortable in LDS per bucket

// ---------------- fallback path (round-2, verified) ----------------
__global__ void zero_out_kernel(float* __restrict__ out, int n) {
    int i = blockIdx.x * blockDim.x + threadIdx.x;
    if (i < n) out[i] = 0.0f;
}

__global__ void scatter_add_kernel(const float* __restrict__ x,
                                   const int* __restrict__ src,
                                   const int* __restrict__ tgt,
                                   const float* __restrict__ e,
                                   float* __restrict__ out,
                                   int n_edges) {
    long long gid   = (long long)blockIdx.x * blockDim.x + threadIdx.x;
    long long total = (long long)n_edges * D_FEAT;
    if (gid >= total) return;
    int edge = (int)(gid >> 5);
    int f    = (int)(gid & 31);
    float m = x[(long long)src[edge] * D_FEAT + f] * e[edge];
    atomicAdd(&out[(long long)tgt[edge] * D_FEAT + f], m);
}

// ---------------- radix path ----------------

// per-chunk histogram of target buckets -> Hg[bucket*nchunks + chunk]
__global__ __launch_bounds__(1024) void p1_hist_kernel(
        const int* __restrict__ tgt, int* __restrict__ Hg,
        int n_edges, int NB, int nchunks) {
    __shared__ int cnt[MAXNB];
    for (int i = threadIdx.x; i < NB; i += 1024) cnt[i] = 0;
    __syncthreads();
    int base = blockIdx.x * CHUNK;
    int lim  = min(base + CHUNK, n_edges);
    for (int i = base + threadIdx.x; i < lim; i += 1024)
        atomicAdd(&cnt[tgt[i] >> SHIFT], 1);
    __syncthreads();
    for (int i = threadIdx.x; i < NB; i += 1024)
        Hg[i * nchunks + blockIdx.x] = cnt[i];
}

// in-place per-256-chunk exclusive scan; chunk totals to bsum
__global__ void scan_block_kernel(int* __restrict__ data, int* __restrict__ bsum,
                                  int n) {
    __shared__ int s[256];
    int i = blockIdx.x * 256 + threadIdx.x;
    int v = (i < n) ? data[i] : 0;
    s[threadIdx.x] = v;
    __syncthreads();
    #pragma unroll
    for (int d = 1; d < 256; d <<= 1) {
        int t = (threadIdx.x >= d) ? s[threadIdx.x - d] : 0;
        __syncthreads();
        s[threadIdx.x] += t;
        __syncthreads();
    }
    if (i < n) data[i] = s[threadIdx.x] - v;           // exclusive within chunk
    if (threadIdx.x == 255) bsum[blockIdx.x] = s[255]; // chunk total
}

__global__ void scan_bsum_kernel(int* __restrict__ bsum, int nblk) {
    __shared__ int s[1024];
    int tid = threadIdx.x;
    int v = (tid < nblk) ? bsum[tid] : 0;
    s[tid] = v;
    __syncthreads();
    for (int d = 1; d < 1024; d <<= 1) {
        int t = (tid >= d) ? s[tid - d] : 0;
        __syncthreads();
        s[tid] += t;
        __syncthreads();
    }
    if (tid < nblk) bsum[tid] = s[tid] - v;            // exclusive
}

__global__ void add_base_kernel(int* __restrict__ data, const int* __restrict__ bsum,
                                int n) {
    int i = blockIdx.x * 256 + threadIdx.x;
    if (i < n) data[i] += bsum[blockIdx.x];
}

// scatter records into (chunk,bucket)-exclusive regions via LDS cursors.
// rec = { src | (local_tgt << 17) , bits(e) }  (src < 2^17, local_tgt < 128)
__global__ __launch_bounds__(1024) void p1_scatter_kernel(
        const int* __restrict__ src,
        const int* __restrict__ tgt,
        const float* __restrict__ e,
        const int* __restrict__ Hg,
        int2* __restrict__ rec,
        int n_edges, int NB, int nchunks) {
    __shared__ int cur[MAXNB];
    for (int i = threadIdx.x; i < NB; i += 1024)
        cur[i] = Hg[i * nchunks + blockIdx.x];
    __syncthreads();
    int base = blockIdx.x * CHUNK;
    int lim  = min(base + CHUNK, n_edges);
    for (int i = base + threadIdx.x; i < lim; i += 1024) {
        int t = tgt[i];
        int b = t >> SHIFT;
        int pos = atomicAdd(&cur[b], 1);
        rec[pos] = make_int2(src[i] | ((t & (BNODES - 1)) << 17),
                             __float_as_int(e[i]));
    }
}

// one 1024-thread block per bucket:
//  fast path: node-sort records into LDS, then register-accumulated gather
//  slow path (bucket > CAP records; unreachable for this input): ds_add acc
__global__ __launch_bounds__(1024) void p2_apply_kernel(
        const float* __restrict__ x, const int2* __restrict__ rec,
        const int* __restrict__ Hg, float* __restrict__ out,
        int n_edges, int n_nodes, int NB, int nchunks) {
    __shared__ int2 srt[CAP];          // 32 KB; aliased as fp32 acc in slow path
    __shared__ int  cnt[BNODES];
    __shared__ int  off[BNODES + 1];
    __shared__ int  cur[BNODES];
    __shared__ int  stmp[BNODES];

    int tid  = threadIdx.x;
    int b    = blockIdx.x;
    int base = Hg[b * nchunks];
    int end  = (b + 1 < NB) ? Hg[(b + 1) * nchunks] : n_edges;
    int nrec = end - base;

    if (nrec <= CAP) {
        // ---- pass 1: per-node counts (small LDS histogram) ----
        if (tid < BNODES) cnt[tid] = 0;
        __syncthreads();
        for (int r = base + tid; r < end; r += 1024) {
            int2 a = rec[r];
            atomicAdd(&cnt[(a.x >> 17) & (BNODES - 1)], 1);
        }
        __syncthreads();
        // ---- 128-entry exclusive scan ----
        int v = (tid < BNODES) ? cnt[tid] : 0;
        if (tid < BNODES) stmp[tid] = v;
        __syncthreads();
        #pragma unroll
        for (int d = 1; d < BNODES; d <<= 1) {
            int t = (tid < BNODES && tid >= d) ? stmp[tid - d] : 0;
            __syncthreads();
            if (tid < BNODES) stmp[tid] += t;
            __syncthreads();
        }
        if (tid < BNODES) { off[tid] = stmp[tid] - v; cur[tid] = stmp[tid] - v; }
        if (tid == 0) off[BNODES] = nrec;
        __syncthreads();
        // ---- pass 2: scatter records node-sorted into LDS ----
        for (int r = base + tid; r < end; r += 1024) {
            int2 a = rec[r];
            int pos = atomicAdd(&cur[(a.x >> 17) & (BNODES - 1)], 1);
            srt[pos] = a;
        }
        __syncthreads();
        // ---- gather: 32 groups x 4 nodes, register accumulate ----
        int f = tid & 31;
        int g = tid >> 5;
        for (int ln = g; ln < BNODES; ln += 32) {
            int p  = off[ln];
            int pe = off[ln + 1];
            float acc = 0.0f;
            for (; p + 3 < pe; p += 4) {      // 4 independent gathers in flight
                int2 r0 = srt[p];
                int2 r1 = srt[p + 1];
                int2 r2 = srt[p + 2];
                int2 r3 = srt[p + 3];
                float v0 = x[(r0.x & 0x1FFFF) * D_FEAT + f] * __int_as_float(r0.y);
                float v1 = x[(r1.x & 0x1FFFF) * D_FEAT + f] * __int_as_float(r1.y);
                float v2 = x[(r2.x & 0x1FFFF) * D_FEAT + f] * __int_as_float(r2.y);
                float v3 = x[(r3.x & 0x1FFFF) * D_FEAT + f] * __int_as_float(r3.y);
                acc += (v0 + v1) + (v2 + v3);
            }
            for (; p < pe; ++p) {
                int2 r0 = srt[p];
                acc += x[(r0.x & 0x1FFFF) * D_FEAT + f] * __int_as_float(r0.y);
            }
            int node = (b << SHIFT) + ln;
            if (node < n_nodes)
                out[(long long)node * D_FEAT + f] = acc;   // zero for isolated nodes
        }
    } else {
        // ---- slow path: LDS fp32 accumulate (correctness only) ----
        float* accS = (float*)srt;     // 16 KB of the 32 KB buffer
        for (int i = tid; i < BNODES * D_FEAT; i += 1024) accS[i] = 0.0f;
        __syncthreads();
        int f = tid & 31;
        for (int r = base + (tid >> 5); r < end; r += 32) {
            int2 a = rec[r];
            float v = x[(a.x & 0x1FFFF) * D_FEAT + f] * __int_as_float(a.y);
            atomicAdd(&accS[((a.x >> 17) & (BNODES - 1)) * D_FEAT + f], v);
        }
        __syncthreads();
        int out0 = b << SHIFT;
        for (int i = tid; i < BNODES * D_FEAT; i += 1024) {
            int node = out0 + (i >> 5);
            if (node < n_nodes) out[(long long)out0 * D_FEAT + i] = accS[i];
        }
    }
}

extern "C" void kernel_launch(void* const* d_in, const int* in_sizes, int n_in,
                              void* d_out, int out_size, void* d_ws, size_t ws_size,
                              hipStream_t stream) {
    const float* x = (const float*)d_in[0];
    const int*   a = (const int*)d_in[1];     // [2, n_edges] delivered as int32
    const float* e = (const float*)d_in[2];

    int n_edges = in_sizes[2];
    int n_nodes = out_size / D_FEAT;
    const int* src = a;
    const int* tgt = a + n_edges;
    float* out = (float*)d_out;

    int NB        = (n_nodes + BNODES - 1) >> SHIFT;
    int nchunks   = (n_edges + CHUNK - 1) / CHUNK;
    int scan_n    = NB * nchunks;
    int nblk_scan = (scan_n + 255) / 256;

    size_t rec_bytes  = (size_t)n_edges * sizeof(int2);
    size_t hg_bytes   = (size_t)scan_n * sizeof(int);
    size_t bsum_bytes = (size_t)nblk_scan * sizeof(int);
    size_t need = rec_bytes + hg_bytes + bsum_bytes;

    bool ok = (ws_size >= need) && (NB <= MAXNB) && (nblk_scan <= 1024) &&
              (n_nodes <= (1 << 17));
    if (!ok) {
        // fallback: direct atomics (verified round 2, 171 us)
        int threads = 256;
        zero_out_kernel<<<(out_size + threads - 1) / threads, threads, 0, stream>>>(out, out_size);
        long long total = (long long)n_edges * D_FEAT;
        int blocks = (int)((total + threads - 1) / threads);
        scatter_add_kernel<<<blocks, threads, 0, stream>>>(x, src, tgt, e, out, n_edges);
        return;
    }

    char* p = (char*)d_ws;
    int2* rec  = (int2*)p; p += rec_bytes;   // 8B-aligned first
    int*  Hg   = (int*)p;  p += hg_bytes;
    int*  bsum = (int*)p;

    p1_hist_kernel<<<nchunks, 1024, 0, stream>>>(tgt, Hg, n_edges, NB, nchunks);
    scan_block_kernel<<<nblk_scan, 256, 0, stream>>>(Hg, bsum, scan_n);
    scan_bsum_kernel<<<1, 1024, 0, stream>>>(bsum, nblk_scan);
    add_base_kernel<<<nblk_scan, 256, 0, stream>>>(Hg, bsum, scan_n);
    p1_scatter_kernel<<<nchunks, 1024, 0, stream>>>(src, tgt, e, Hg, rec, n_edges, NB, nchunks);
    p2_apply_kernel<<<NB, 1024, 0, stream>>>(x, rec, Hg, out, n_edges, n_nodes, NB, nchunks);
}